// Round 9
// baseline (106.820 us; speedup 1.0000x reference)
//
#include <hip/hip_runtime.h>
#include <float.h>

// Problem constants (B=16, N=M=4096, fp32, 3-D points)
#define BATCH  16
#define NPTS   4096
#define TOTALP (BATCH * NPTS)      // 65536 points per set
#define NQ     (2 * TOTALP)       // 131072 query slots (both dirs)

typedef _Float16 half8  __attribute__((ext_vector_type(8)));
typedef float    f32x16 __attribute__((ext_vector_type(16)));

// Order-preserving float->uint encode (unsigned compare == float compare).
__device__ __forceinline__ unsigned enc(float f)
{
    unsigned b = __float_as_uint(f);
    return (b & 0x80000000u) ? ~b : (b | 0x80000000u);
}
__device__ __forceinline__ float dec(unsigned k)
{
    return (k & 0x80000000u) ? __uint_as_float(k & 0x7FFFFFFFu)
                             : __uint_as_float(~k);
}

// min with DPP-shifted value; old = v so non-receiving lanes are harmless.
template <int CTRL>
__device__ __forceinline__ float dpp_min(float v)
{
    int o = __builtin_amdgcn_update_dpp(__float_as_int(v), __float_as_int(v),
                                        CTRL, 0xF, 0xF, false);
    return fminf(v, __int_as_float(o));
}

union RecHalf { _Float16 h[8]; uint4 u; };

// Build the K=16 record halves.
// A row (u = -2x): h0 = uxh uyh uzh uxl uyl uzl uxh uyh
//                  h1 = uzh uxl uyl uzl sh  sl  1   1
// B col (v =  p):  h0 = vxh vyh vzh vxh vyh vzh vxl vyl
//                  h1 = vzl vxl vyl vzl 1   1   sh  sl
// sum_k A_k B_k = u.v + sq_i + sq_j = ||x-p||^2 exactly in one K=16 dot.
__device__ __forceinline__ void make_recA(float x, float y, float z,
                                          uint4& h0, uint4& h1)
{
    const float ux = -2.0f * x, uy = -2.0f * y, uz = -2.0f * z;
    const _Float16 uxh = (_Float16)ux, uyh = (_Float16)uy, uzh = (_Float16)uz;
    const _Float16 uxl = (_Float16)(ux - (float)uxh);
    const _Float16 uyl = (_Float16)(uy - (float)uyh);
    const _Float16 uzl = (_Float16)(uz - (float)uzh);
    const float sq = x * x + y * y + z * z;
    const _Float16 sh = (_Float16)sq;
    const _Float16 sl = (_Float16)(sq - (float)sh);
    const _Float16 one = (_Float16)1.0f;
    RecHalf r0, r1;
    r0.h[0] = uxh; r0.h[1] = uyh; r0.h[2] = uzh; r0.h[3] = uxl;
    r0.h[4] = uyl; r0.h[5] = uzl; r0.h[6] = uxh; r0.h[7] = uyh;
    r1.h[0] = uzh; r1.h[1] = uxl; r1.h[2] = uyl; r1.h[3] = uzl;
    r1.h[4] = sh;  r1.h[5] = sl;  r1.h[6] = one; r1.h[7] = one;
    h0 = r0.u; h1 = r1.u;
}

__device__ __forceinline__ void make_recB(float x, float y, float z,
                                          uint4& h0, uint4& h1)
{
    const _Float16 vxh = (_Float16)x, vyh = (_Float16)y, vzh = (_Float16)z;
    const _Float16 vxl = (_Float16)(x - (float)vxh);
    const _Float16 vyl = (_Float16)(y - (float)vyh);
    const _Float16 vzl = (_Float16)(z - (float)vzh);
    const float sq = x * x + y * y + z * z;
    const _Float16 sh = (_Float16)sq;
    const _Float16 sl = (_Float16)(sq - (float)sh);
    const _Float16 one = (_Float16)1.0f;
    RecHalf r0, r1;
    r0.h[0] = vxh; r0.h[1] = vyh; r0.h[2] = vzh; r0.h[3] = vxh;
    r0.h[4] = vyh; r0.h[5] = vzh; r0.h[6] = vxl; r0.h[7] = vyl;
    r1.h[0] = vzl; r1.h[1] = vxl; r1.h[2] = vyl; r1.h[3] = vzl;
    r1.h[4] = one; r1.h[5] = one; r1.h[6] = sh;  r1.h[7] = sl;
    h0 = r0.u; h1 = r1.u;
}

// ---------------------------------------------------------------------------
// MFMA chamfer kernel, 32x32x16 f16 (K=16 fully used, zero waste).
//   blk = ((dir*16 + b)*8 + rb)*8 + cc   (ALL selectors block-uniform)
//   Block: 512 rows x 512 cols; 4 waves x 4 row-tiles (128 rows each).
// Fragment layouts:
//   A: m=lane&31, k=(lane>>5)*8+j  -> lane reads Ast[lane>>5][row] (16B)
//   B: n=lane&31, k=(lane>>5)*8+j  -> lane reads Bst[lane>>5][col]
//   D: col=lane&31, row=(reg&3)+8*(reg>>2)+4*(lane>>5)  [verified m74/m101]
// LDS planes split by K-half -> frag reads are stride-1 b128, conflict-free.
// Hot loop: 2 col-tiles/step, min3(d0,d1,acc) halves the fmin count.
// Row-min: 4 DPP butterfly steps + row_bcast15 merge -> lanes 16/48 hold the
// 32-col min; merged across blocks via atomicMin on uint-encoded keys.
// ---------------------------------------------------------------------------
__global__ __launch_bounds__(256) void chamfer_mfma32(
    const float* __restrict__ xyz1, const float* __restrict__ xyz2,
    unsigned* __restrict__ keys)
{
    __shared__ uint4 Ast[2][512];    // [K-half][row], 16 KiB
    __shared__ uint4 Bst[2][512];    // [K-half][col], 16 KiB

    const int blk = blockIdx.x;
    const int cc  = blk & 7;
    const int rb  = (blk >> 3) & 7;
    const int b   = (blk >> 6) & 15;
    const int dir = blk >> 10;                 // block-uniform

    const float* __restrict__ rowsrc = (dir == 0 ? xyz1 : xyz2) + (size_t)b * NPTS * 3;
    const float* __restrict__ colsrc = (dir == 0 ? xyz2 : xyz1) + (size_t)b * NPTS * 3;
    const int rowbase = rb << 9;
    const int colbase = cc << 9;

    // ---- stage A and B (512 each, 2 per thread) ----
    for (int r = threadIdx.x; r < 512; r += 256) {
        uint4 h0, h1;
        make_recA(rowsrc[3 * (rowbase + r) + 0],
                  rowsrc[3 * (rowbase + r) + 1],
                  rowsrc[3 * (rowbase + r) + 2], h0, h1);
        Ast[0][r] = h0; Ast[1][r] = h1;
    }
    for (int c = threadIdx.x; c < 512; c += 256) {
        uint4 h0, h1;
        make_recB(colsrc[3 * (colbase + c) + 0],
                  colsrc[3 * (colbase + c) + 1],
                  colsrc[3 * (colbase + c) + 2], h0, h1);
        Bst[0][c] = h0; Bst[1][c] = h1;
    }
    __syncthreads();

    const int lane = threadIdx.x & 63;
    const int wv   = threadIdx.x >> 6;
    const int n32  = lane & 31;
    const int half = lane >> 5;

    // ---- A fragments: 4 row-tiles (128 rows) per wave ----
    half8 afrag[4];
#pragma unroll
    for (int t = 0; t < 4; ++t)
        afrag[t] = __builtin_bit_cast(
            half8, Ast[half][wv * 128 + t * 32 + n32]);

    f32x16 acc[4];
#pragma unroll
    for (int t = 0; t < 4; ++t)
#pragma unroll
        for (int r = 0; r < 16; ++r) acc[t][r] = FLT_MAX;

    f32x16 cz;
#pragma unroll
    for (int r = 0; r < 16; ++r) cz[r] = 0.0f;

    // ---- hot loop: 8 steps x (2 b128 reads + 8 MFMA + 64 min3) ----
    for (int s = 0; s < 8; ++s) {
        const half8 bf0 = __builtin_bit_cast(
            half8, Bst[half][(2 * s + 0) * 32 + n32]);
        const half8 bf1 = __builtin_bit_cast(
            half8, Bst[half][(2 * s + 1) * 32 + n32]);
#pragma unroll
        for (int t = 0; t < 4; ++t) {
            f32x16 d0 = __builtin_amdgcn_mfma_f32_32x32x16_f16(afrag[t], bf0, cz, 0, 0, 0);
            f32x16 d1 = __builtin_amdgcn_mfma_f32_32x32x16_f16(afrag[t], bf1, cz, 0, 0, 0);
#pragma unroll
            for (int r = 0; r < 16; ++r)
                acc[t][r] = fminf(fminf(d0[r], d1[r]), acc[t][r]);   // v_min3
        }
    }

    // ---- epilogue: 32-col min via DPP, then atomicMin per row ----
    const unsigned kbase = ((unsigned)dir << 16) + ((unsigned)b << 12)
                         + (unsigned)rowbase + (unsigned)(wv * 128);
#pragma unroll
    for (int t = 0; t < 4; ++t) {
#pragma unroll
        for (int r = 0; r < 16; ++r) {
            float v = acc[t][r];
            v = dpp_min<0xB1>(v);     // quad_perm xor1
            v = dpp_min<0x4E>(v);     // quad_perm xor2
            v = dpp_min<0x124>(v);    // row_ror:4
            v = dpp_min<0x128>(v);    // row_ror:8  -> min within 16-lane row
            v = dpp_min<0x142>(v);    // row_bcast15 -> lanes 16-31/48-63 full
            if ((lane & 31) == 16) {  // lanes 16 (half 0) and 48 (half 1)
                const int rowq = (r & 3) + 8 * (r >> 2) + 4 * half;
                atomicMin(&keys[kbase + t * 32 + rowq], enc(v));
            }
        }
    }
}

// ---------------------------------------------------------------------------
// Final kernel: 512 blocks x 256, dir block-uniform. Decode per-query min,
// block-reduce sum, one atomicAdd per block into out[dir].
// ---------------------------------------------------------------------------
__global__ __launch_bounds__(256) void chamfer_final_atomic(
    const unsigned* __restrict__ keys, float* __restrict__ out)
{
    const int dir = blockIdx.x >> 8;                       // block-uniform
    const int qi  = ((blockIdx.x & 255) << 8) + threadIdx.x;
    const int q   = (dir << 16) + qi;

    float d = dec(keys[q]);

    for (int off = 32; off > 0; off >>= 1)
        d += __shfl_down(d, off);

    __shared__ float wsum[4];
    const int lane = threadIdx.x & 63;
    const int wv   = threadIdx.x >> 6;
    if (lane == 0) wsum[wv] = d;
    __syncthreads();
    if (threadIdx.x == 0) {
        float s = wsum[0] + wsum[1] + wsum[2] + wsum[3];
        atomicAdd(&out[dir], s * (1.0f / (float)TOTALP));
    }
}

// ---------------------------------------------------------------------------
// Fallback for tiny workspace: direct 7-op kernel, no ws needed.
// ---------------------------------------------------------------------------
__global__ void zero_out_kernel(float* __restrict__ out)
{
    if (threadIdx.x == 0) { out[0] = 0.0f; out[1] = 0.0f; }
}

__global__ __launch_bounds__(256) void chamfer_raw_kernel(
    const float* __restrict__ xyz1, const float* __restrict__ xyz2,
    float* __restrict__ out)
{
    const int blk = blockIdx.x;
    const int dir = blk >> 8;
    const int idx = blk & 255;
    const int b   = idx >> 4;
    const int n0  = (idx & 15) << 8;

    const float* __restrict__ own = (dir == 0 ? xyz1 : xyz2) + (size_t)b * NPTS * 3;
    const float* __restrict__ opp = (dir == 0 ? xyz2 : xyz1) + (size_t)b * NPTS * 3;

    const int n = n0 + threadIdx.x;
    const float ax = own[3 * n + 0];
    const float ay = own[3 * n + 1];
    const float az = own[3 * n + 2];

    float best = FLT_MAX;
    for (int m = 0; m < NPTS; m += 4) {
#pragma unroll
        for (int u = 0; u < 4; ++u) {
            const float px = opp[3 * (m + u) + 0];
            const float py = opp[3 * (m + u) + 1];
            const float pz = opp[3 * (m + u) + 2];
            const float dx = px - ax, dy = py - ay, dz = pz - az;
            float d = dx * dx;
            d = fmaf(dy, dy, d);
            d = fmaf(dz, dz, d);
            best = fminf(best, d);
        }
    }

    float d = best;
    for (int off = 32; off > 0; off >>= 1)
        d += __shfl_down(d, off);

    __shared__ float wsum[4];
    const int lane = threadIdx.x & 63;
    const int wv   = threadIdx.x >> 6;
    if (lane == 0) wsum[wv] = d;
    __syncthreads();
    if (threadIdx.x == 0) {
        float s = wsum[0] + wsum[1] + wsum[2] + wsum[3];
        atomicAdd(&out[dir], s * (1.0f / (float)TOTALP));
    }
}

// ---------------------------------------------------------------------------
extern "C" void kernel_launch(void* const* d_in, const int* in_sizes, int n_in,
                              void* d_out, int out_size, void* d_ws, size_t ws_size,
                              hipStream_t stream)
{
    const float* xyz1 = (const float*)d_in[0];
    const float* xyz2 = (const float*)d_in[1];
    float* out = (float*)d_out;

    const size_t keys_bytes = (size_t)NQ * sizeof(unsigned);  // 512 KiB

    if (ws_size >= keys_bytes) {
        unsigned* keys = (unsigned*)d_ws;
        hipMemsetAsync(keys, 0xFF, keys_bytes, stream);       // keys = +inf
        hipMemsetAsync(out, 0, 2 * sizeof(float), stream);
        // 2048 blocks: dir(2) x b(16) x rb(8) x cc(8)
        chamfer_mfma32<<<2048, 256, 0, stream>>>(xyz1, xyz2, keys);
        chamfer_final_atomic<<<NQ / 256, 256, 0, stream>>>(keys, out);
    } else {
        zero_out_kernel<<<1, 64, 0, stream>>>(out);
        chamfer_raw_kernel<<<512, 256, 0, stream>>>(xyz1, xyz2, out);
    }
}

// Round 10
// 95.508 us; speedup vs baseline: 1.1184x; 1.1184x over previous
//
#include <hip/hip_runtime.h>
#include <float.h>

// Problem constants (B=16, N=M=4096, fp32, 3-D points)
#define BATCH  16
#define NPTS   4096
#define TOTALP (BATCH * NPTS)      // 65536 points per set
#define NQ     (2 * TOTALP)       // 131072 query slots (both dirs)

typedef _Float16 half8  __attribute__((ext_vector_type(8)));
typedef float    f32x16 __attribute__((ext_vector_type(16)));

#define ONE2 0x3C003C00u          // two packed f16 1.0

// Order-preserving float->uint encode (unsigned compare == float compare).
__device__ __forceinline__ unsigned enc(float f)
{
    unsigned b = __float_as_uint(f);
    return (b & 0x80000000u) ? ~b : (b | 0x80000000u);
}
__device__ __forceinline__ float dec(unsigned k)
{
    return (k & 0x80000000u) ? __uint_as_float(k & 0x7FFFFFFFu)
                             : __uint_as_float(~k);
}

__device__ __forceinline__ unsigned pk(_Float16 lo, _Float16 hi)
{
    const unsigned a = (unsigned)__builtin_bit_cast(unsigned short, lo);
    const unsigned b = (unsigned)__builtin_bit_cast(unsigned short, hi);
    return a | (b << 16);
}

// In-register min of 16 MFMA outputs + running acc: 8 x v_min3_f32.
__device__ __forceinline__ float min16(const f32x16& d, float acc)
{
    const float m1 = fminf(fminf(d[0],  d[1]),  d[2]);
    const float m2 = fminf(fminf(d[3],  d[4]),  d[5]);
    const float m3 = fminf(fminf(d[6],  d[7]),  d[8]);
    const float m4 = fminf(fminf(d[9],  d[10]), d[11]);
    const float m5 = fminf(fminf(d[12], d[13]), d[14]);
    const float m6 = fminf(fminf(m1, m2), m3);
    const float m7 = fminf(fminf(m4, m5), d[15]);
    return fminf(fminf(m6, m7), acc);
}

// ---------------------------------------------------------------------------
// Prep kernel: pack every point (both sets) into minimal 16 B f16 records.
//   Q rec (query role, u = -2x):  d = { uxh|uyh, uzh|uxl, uyl|uzl, sh|sl }
//   O rec (opp   role, v =  x):   d = { vxh|vyh, vzh|vxl, vyl|vzl, sh|sl }
// hi/lo f16 split: c = ch + cl exactly (to f16 double-precision); sq split
// likewise. One K=16 f16 dot then yields ||x-p||^2 (R8/R9: absmax == 0).
// ---------------------------------------------------------------------------
__global__ __launch_bounds__(256) void prep_kernel(
    const float* __restrict__ xyz1, const float* __restrict__ xyz2,
    uint4* __restrict__ packQ, uint4* __restrict__ packO)
{
    const int i = blockIdx.x * 256 + threadIdx.x;    // 0..131071
    const float* src = (i < TOTALP) ? xyz1 : xyz2;
    const int p = i & (TOTALP - 1);
    const float x = src[3 * p + 0];
    const float y = src[3 * p + 1];
    const float z = src[3 * p + 2];
    const float sq = x * x + y * y + z * z;
    const _Float16 sh = (_Float16)sq;
    const _Float16 sl = (_Float16)(sq - (float)sh);

    // O record (v = x)
    const _Float16 vxh = (_Float16)x, vyh = (_Float16)y, vzh = (_Float16)z;
    const _Float16 vxl = (_Float16)(x - (float)vxh);
    const _Float16 vyl = (_Float16)(y - (float)vyh);
    const _Float16 vzl = (_Float16)(z - (float)vzh);
    packO[i] = make_uint4(pk(vxh, vyh), pk(vzh, vxl), pk(vyl, vzl), pk(sh, sl));

    // Q record (u = -2x)
    const float ux = -2.0f * x, uy = -2.0f * y, uz = -2.0f * z;
    const _Float16 uxh = (_Float16)ux, uyh = (_Float16)uy, uzh = (_Float16)uz;
    const _Float16 uxl = (_Float16)(ux - (float)uxh);
    const _Float16 uyl = (_Float16)(uy - (float)uyh);
    const _Float16 uzl = (_Float16)(uz - (float)uzh);
    packQ[i] = make_uint4(pk(uxh, uyh), pk(uzh, uxl), pk(uyl, uzl), pk(sh, sl));
}

// ---------------------------------------------------------------------------
// Flipped MFMA chamfer: A = opp points (rows, streamed via LDS),
// B = query points (cols, held in registers). 32x32x16 f16, K=16 full.
//   K-slot pairing (A h0|h1 vs B h0|h1):
//     A: [vxh vyh vzh vxh vyh vzh vxl vyl | vzl vxl vyl vzl 1 1 sh sl]
//     B: [uxh uyh uzh uxl uyl uzl uxh uyh | uzh uxl uyl uzl sh sl 1 1]
//   sum_k A_k B_k = u.v + sq_q + sq_o = ||x - p||^2.
// D layout (verified m74/m101 + R9 absmax=0): col(query)=lane&31,
// row(opp)=(reg&3)+8*(reg>>2)+4*(lane>>5) -> min over 16 regs is IN-REGISTER;
// lanes i,i+32 hold complementary opp rows of the same query -> one
// shfl_xor(32) + atomicMin finishes the query. No cross-lane DPP tree.
//   blk = ((dir*16 + b)*8 + qc)*4 + ch     (ALL selectors block-uniform)
//   Block: 512 queries (4 waves x 4 frags x 32 cols) x 1024 opp points
//   (2 staging rounds of 512 recs = 16 KiB LDS, expanded from minimal recs).
// ---------------------------------------------------------------------------
__global__ __launch_bounds__(256) void chamfer_flip(
    const uint4* __restrict__ packQ, const uint4* __restrict__ packO,
    unsigned* __restrict__ keys)
{
    __shared__ uint4 Ast[2][512];    // [K-half][rec], 16 KiB

    const int blk = blockIdx.x;
    const int ch  = blk & 3;
    const int qc  = (blk >> 2) & 7;
    const int b   = (blk >> 5) & 15;
    const int dir = blk >> 9;                    // block-uniform

    const int lane = threadIdx.x & 63;
    const int wv   = threadIdx.x >> 6;
    const int n32  = lane & 31;
    const int half = lane >> 5;

    // ---- load 4 query B-fragments (zero-shuffle assembly) ----
    const int qbase = dir * TOTALP + b * NPTS + qc * 512 + wv * 128;
    half8 bfrag[4];
#pragma unroll
    for (int qf = 0; qf < 4; ++qf) {
        const uint4 d = packQ[qbase + qf * 32 + n32];
        const uint4 u = half ? make_uint4(d.y, d.z, d.w, ONE2)
                             : make_uint4(d.x, d.y, d.z, d.x);
        bfrag[qf] = __builtin_bit_cast(half8, u);
    }

    float acc[4];
#pragma unroll
    for (int qf = 0; qf < 4; ++qf) acc[qf] = FLT_MAX;

    f32x16 cz;
#pragma unroll
    for (int r = 0; r < 16; ++r) cz[r] = 0.0f;

    const int obase = (dir ^ 1) * TOTALP + b * NPTS + ch * 1024;

    for (int round = 0; round < 2; ++round) {
        __syncthreads();
        // ---- stage 512 opp recs: minimal 16B -> expanded 32B A-layout ----
        for (int r = threadIdx.x; r < 512; r += 256) {
            const uint4 d = packO[obase + round * 512 + r];
            uint4 h0, h1;
            h0.x = d.x;                                   // vxh vyh
            h0.y = (d.y & 0xFFFFu) | (d.x << 16);         // vzh vxh
            h0.z = (d.x >> 16) | (d.y << 16);             // vyh vzh
            h0.w = (d.y >> 16) | (d.z << 16);             // vxl vyl
            h1.x = (d.z >> 16) | (d.y & 0xFFFF0000u);     // vzl vxl
            h1.y = d.z;                                   // vyl vzl
            h1.z = ONE2;                                  // 1   1
            h1.w = d.w;                                   // sh  sl
            Ast[0][r] = h0;
            Ast[1][r] = h1;
        }
        __syncthreads();

        // ---- 16 tiles x (1 ds_read_b128 + 4 MFMA + 32 min3) ----
        for (int tile = 0; tile < 16; ++tile) {
            const half8 af = __builtin_bit_cast(
                half8, Ast[half][tile * 32 + n32]);
#pragma unroll
            for (int qf = 0; qf < 4; ++qf) {
                const f32x16 dd = __builtin_amdgcn_mfma_f32_32x32x16_f16(
                    af, bfrag[qf], cz, 0, 0, 0);
                acc[qf] = min16(dd, acc[qf]);
            }
        }
    }

    // ---- epilogue: merge row-halves, one atomicMin per query ----
#pragma unroll
    for (int qf = 0; qf < 4; ++qf) {
        float v = acc[qf];
        v = fminf(v, __shfl_xor(v, 32));
        if (lane < 32)
            atomicMin(&keys[qbase + qf * 32 + n32], enc(v));
    }
}

// ---------------------------------------------------------------------------
// Final kernel: 512 blocks x 256, dir block-uniform. Decode per-query min,
// block-reduce sum, one atomicAdd per block into out[dir].
// ---------------------------------------------------------------------------
__global__ __launch_bounds__(256) void chamfer_final_atomic(
    const unsigned* __restrict__ keys, float* __restrict__ out)
{
    const int dir = blockIdx.x >> 8;                       // block-uniform
    const int qi  = ((blockIdx.x & 255) << 8) + threadIdx.x;
    const int q   = (dir << 16) + qi;

    float d = dec(keys[q]);

    for (int off = 32; off > 0; off >>= 1)
        d += __shfl_down(d, off);

    __shared__ float wsum[4];
    const int lane = threadIdx.x & 63;
    const int wv   = threadIdx.x >> 6;
    if (lane == 0) wsum[wv] = d;
    __syncthreads();
    if (threadIdx.x == 0) {
        float s = wsum[0] + wsum[1] + wsum[2] + wsum[3];
        atomicAdd(&out[dir], s * (1.0f / (float)TOTALP));
    }
}

// ---------------------------------------------------------------------------
// Fallback for tiny workspace: direct 7-op kernel, no ws needed.
// ---------------------------------------------------------------------------
__global__ void zero_out_kernel(float* __restrict__ out)
{
    if (threadIdx.x == 0) { out[0] = 0.0f; out[1] = 0.0f; }
}

__global__ __launch_bounds__(256) void chamfer_raw_kernel(
    const float* __restrict__ xyz1, const float* __restrict__ xyz2,
    float* __restrict__ out)
{
    const int blk = blockIdx.x;
    const int dir = blk >> 8;
    const int idx = blk & 255;
    const int b   = idx >> 4;
    const int n0  = (idx & 15) << 8;

    const float* __restrict__ own = (dir == 0 ? xyz1 : xyz2) + (size_t)b * NPTS * 3;
    const float* __restrict__ opp = (dir == 0 ? xyz2 : xyz1) + (size_t)b * NPTS * 3;

    const int n = n0 + threadIdx.x;
    const float ax = own[3 * n + 0];
    const float ay = own[3 * n + 1];
    const float az = own[3 * n + 2];

    float best = FLT_MAX;
    for (int m = 0; m < NPTS; m += 4) {
#pragma unroll
        for (int u = 0; u < 4; ++u) {
            const float px = opp[3 * (m + u) + 0];
            const float py = opp[3 * (m + u) + 1];
            const float pz = opp[3 * (m + u) + 2];
            const float dx = px - ax, dy = py - ay, dz = pz - az;
            float d = dx * dx;
            d = fmaf(dy, dy, d);
            d = fmaf(dz, dz, d);
            best = fminf(best, d);
        }
    }

    float d = best;
    for (int off = 32; off > 0; off >>= 1)
        d += __shfl_down(d, off);

    __shared__ float wsum[4];
    const int lane = threadIdx.x & 63;
    const int wv   = threadIdx.x >> 6;
    if (lane == 0) wsum[wv] = d;
    __syncthreads();
    if (threadIdx.x == 0) {
        float s = wsum[0] + wsum[1] + wsum[2] + wsum[3];
        atomicAdd(&out[dir], s * (1.0f / (float)TOTALP));
    }
}

// ---------------------------------------------------------------------------
extern "C" void kernel_launch(void* const* d_in, const int* in_sizes, int n_in,
                              void* d_out, int out_size, void* d_ws, size_t ws_size,
                              hipStream_t stream)
{
    const float* xyz1 = (const float*)d_in[0];
    const float* xyz2 = (const float*)d_in[1];
    float* out = (float*)d_out;

    const size_t keys_bytes = (size_t)NQ * sizeof(unsigned);  // 512 KiB
    const size_t pack_bytes = (size_t)NQ * sizeof(uint4);     // 2 MiB each

    if (ws_size >= keys_bytes + 2 * pack_bytes) {             // 4.5 MiB
        unsigned* keys  = (unsigned*)d_ws;
        uint4*    packQ = (uint4*)((char*)d_ws + keys_bytes);
        uint4*    packO = (uint4*)((char*)d_ws + keys_bytes + pack_bytes);

        hipMemsetAsync(keys, 0xFF, keys_bytes, stream);       // keys = +inf
        hipMemsetAsync(out, 0, 2 * sizeof(float), stream);
        prep_kernel<<<NQ / 256, 256, 0, stream>>>(xyz1, xyz2, packQ, packO);
        // 1024 blocks: dir(2) x b(16) x qc(8) x ch(4) -> 4 blocks/CU
        chamfer_flip<<<1024, 256, 0, stream>>>(packQ, packO, keys);
        chamfer_final_atomic<<<NQ / 256, 256, 0, stream>>>(keys, out);
    } else {
        zero_out_kernel<<<1, 64, 0, stream>>>(out);
        chamfer_raw_kernel<<<512, 256, 0, stream>>>(xyz1, xyz2, out);
    }
}

// Round 11
// 94.309 us; speedup vs baseline: 1.1327x; 1.0127x over previous
//
#include <hip/hip_runtime.h>
#include <float.h>

// Problem constants (B=16, N=M=4096, fp32, 3-D points)
#define BATCH  16
#define NPTS   4096
#define TOTALP (BATCH * NPTS)      // 65536 points per set
#define NQ     (2 * TOTALP)       // 131072 point slots (both sets)

typedef _Float16 half8  __attribute__((ext_vector_type(8)));
typedef float    f32x16 __attribute__((ext_vector_type(16)));

#define ONE2 0x3C003C00u          // two packed f16 1.0

// Order-preserving float->uint encode (unsigned compare == float compare).
__device__ __forceinline__ unsigned enc(float f)
{
    unsigned b = __float_as_uint(f);
    return (b & 0x80000000u) ? ~b : (b | 0x80000000u);
}
__device__ __forceinline__ float dec(unsigned k)
{
    return (k & 0x80000000u) ? __uint_as_float(k & 0x7FFFFFFFu)
                             : __uint_as_float(~k);
}

__device__ __forceinline__ unsigned pk(_Float16 lo, _Float16 hi)
{
    const unsigned a = (unsigned)__builtin_bit_cast(unsigned short, lo);
    const unsigned b = (unsigned)__builtin_bit_cast(unsigned short, hi);
    return a | (b << 16);
}

// In-register min of 16 MFMA outputs + running acc: 8 x v_min3_f32.
__device__ __forceinline__ float min16(const f32x16& d, float acc)
{
    const float m1 = fminf(fminf(d[0],  d[1]),  d[2]);
    const float m2 = fminf(fminf(d[3],  d[4]),  d[5]);
    const float m3 = fminf(fminf(d[6],  d[7]),  d[8]);
    const float m4 = fminf(fminf(d[9],  d[10]), d[11]);
    const float m5 = fminf(fminf(d[12], d[13]), d[14]);
    const float m6 = fminf(fminf(m1, m2), m3);
    const float m7 = fminf(fminf(m4, m5), d[15]);
    return fminf(fminf(m6, m7), acc);
}

// ---------------------------------------------------------------------------
// Prep kernel (512 blocks x 256): for every point i of both sets, write
//   packQ[i]  (query record, u = -2x, minimal 16 B; B-frag halves are
//              {d.x,d.y,d.z,d.x} / {d.y,d.z,d.w,1|1} -> zero shuffling)
//   planes[0][i] / planes[1][i]  (opp record pre-expanded in the MFMA
//              A-fragment K-half layout -> flip loads them DIRECTLY from
//              global, perfectly coalesced; no LDS, no staging bitops)
// Also initializes keys[i] = +inf-key and out[0..1] = 0 (poisoned 0xAA),
// replacing both hipMemsetAsync calls.
// One K=16 f16 dot of (A-rec, B-rec) = ||x - p||^2 exactly (R8-R10 absmax=0).
// ---------------------------------------------------------------------------
__global__ __launch_bounds__(256) void prep_kernel(
    const float* __restrict__ xyz1, const float* __restrict__ xyz2,
    uint4* __restrict__ packQ, uint4* __restrict__ planes,
    unsigned* __restrict__ keys, float* __restrict__ out)
{
    const int i = blockIdx.x * 256 + threadIdx.x;    // 0..131071
    if (i == 0) { out[0] = 0.0f; out[1] = 0.0f; }
    keys[i] = 0xFFFFFFFFu;

    const float* src = (i < TOTALP) ? xyz1 : xyz2;
    const int p = i & (TOTALP - 1);
    const float x = src[3 * p + 0];
    const float y = src[3 * p + 1];
    const float z = src[3 * p + 2];
    const float sq = x * x + y * y + z * z;
    const _Float16 sh = (_Float16)sq;
    const _Float16 sl = (_Float16)(sq - (float)sh);

    // Opp-role A-fragment halves (v = x), pre-expanded:
    //   half0 k0-7: vxh vyh vzh vxh vyh vzh vxl vyl
    //   half1 k8-15: vzl vxl vyl vzl 1 1 sh sl
    const _Float16 vxh = (_Float16)x, vyh = (_Float16)y, vzh = (_Float16)z;
    const _Float16 vxl = (_Float16)(x - (float)vxh);
    const _Float16 vyl = (_Float16)(y - (float)vyh);
    const _Float16 vzl = (_Float16)(z - (float)vzh);
    planes[i]      = make_uint4(pk(vxh, vyh), pk(vzh, vxh),
                                pk(vyh, vzh), pk(vxl, vyl));
    planes[NQ + i] = make_uint4(pk(vzl, vxl), pk(vyl, vzl),
                                ONE2,         pk(sh, sl));

    // Query-role record (u = -2x), minimal:
    const float ux = -2.0f * x, uy = -2.0f * y, uz = -2.0f * z;
    const _Float16 uxh = (_Float16)ux, uyh = (_Float16)uy, uzh = (_Float16)uz;
    const _Float16 uxl = (_Float16)(ux - (float)uxh);
    const _Float16 uyl = (_Float16)(uy - (float)uyh);
    const _Float16 uzl = (_Float16)(uz - (float)uzh);
    packQ[i] = make_uint4(pk(uxh, uyh), pk(uzh, uxl), pk(uyl, uzl), pk(sh, sl));
}

// ---------------------------------------------------------------------------
// Barrier-free MFMA chamfer. A = opp points (streamed DIRECTLY from global,
// coalesced b128, wrap-prefetched), B = 4 query frags held in registers.
// 32x32x16 f16, K=16 fully used; D: col(query)=lane&31, row(opp)=reg-mapped
// -> the opp-min is an in-register 8x v_min3 tree per MFMA; epilogue is one
// shfl_xor(32) + atomicMin per query. No LDS. No __syncthreads.
//   blk = ((dir*16 + b)*8 + qc)*8 + ch     (ALL selectors block-uniform)
//   Block: 512 queries (4 waves x 4 frags x 32) x 512 opp points (16 tiles).
//   2048 blocks -> 8 blocks/CU, 32 waves/CU for latency hiding.
// ---------------------------------------------------------------------------
__global__ __launch_bounds__(256) void chamfer_flip2(
    const uint4* __restrict__ packQ, const uint4* __restrict__ planes,
    unsigned* __restrict__ keys)
{
    const int blk = blockIdx.x;
    const int ch  = blk & 7;
    const int qc  = (blk >> 3) & 7;
    const int b   = (blk >> 6) & 15;
    const int dir = blk >> 10;                   // block-uniform

    const int lane = threadIdx.x & 63;
    const int wv   = threadIdx.x >> 6;
    const int n32  = lane & 31;
    const int half = lane >> 5;

    // ---- 4 query B-fragments (zero-shuffle assembly) ----
    const int qbase = dir * TOTALP + b * NPTS + qc * 512 + wv * 128;
    half8 bfrag[4];
#pragma unroll
    for (int qf = 0; qf < 4; ++qf) {
        const uint4 d = packQ[qbase + qf * 32 + n32];
        const uint4 u = half ? make_uint4(d.y, d.z, d.w, ONE2)
                             : make_uint4(d.x, d.y, d.z, d.x);
        bfrag[qf] = __builtin_bit_cast(half8, u);
    }

    float acc[4];
#pragma unroll
    for (int qf = 0; qf < 4; ++qf) acc[qf] = FLT_MAX;

    f32x16 cz;
#pragma unroll
    for (int r = 0; r < 16; ++r) cz[r] = 0.0f;

    // ---- A stream: 16 tiles of 32 recs, coalesced global b128 loads ----
    const uint4* __restrict__ ap =
        planes + (size_t)half * NQ + (dir ^ 1) * TOTALP + b * NPTS + ch * 512;

    uint4 cur = ap[n32];                          // tile 0
    for (int tile = 0; tile < 16; ++tile) {
        const uint4 nxt = ap[(((tile + 1) & 15) * 32) + n32];  // wrap prefetch
        const half8 af = __builtin_bit_cast(half8, cur);
#pragma unroll
        for (int qf = 0; qf < 4; ++qf) {
            const f32x16 dd = __builtin_amdgcn_mfma_f32_32x32x16_f16(
                af, bfrag[qf], cz, 0, 0, 0);
            acc[qf] = min16(dd, acc[qf]);
        }
        cur = nxt;
    }

    // ---- epilogue: merge row-halves, one atomicMin per query ----
#pragma unroll
    for (int qf = 0; qf < 4; ++qf) {
        float v = acc[qf];
        v = fminf(v, __shfl_xor(v, 32));
        if (lane < 32)
            atomicMin(&keys[qbase + qf * 32 + n32], enc(v));
    }
}

// ---------------------------------------------------------------------------
// Final kernel: 512 blocks x 256, dir block-uniform. Decode per-query min,
// block-reduce sum, one atomicAdd per block into out[dir].
// ---------------------------------------------------------------------------
__global__ __launch_bounds__(256) void chamfer_final_atomic(
    const unsigned* __restrict__ keys, float* __restrict__ out)
{
    const int dir = blockIdx.x >> 8;                       // block-uniform
    const int qi  = ((blockIdx.x & 255) << 8) + threadIdx.x;
    const int q   = (dir << 16) + qi;

    float d = dec(keys[q]);

    for (int off = 32; off > 0; off >>= 1)
        d += __shfl_down(d, off);

    __shared__ float wsum[4];
    const int lane = threadIdx.x & 63;
    const int wv   = threadIdx.x >> 6;
    if (lane == 0) wsum[wv] = d;
    __syncthreads();
    if (threadIdx.x == 0) {
        float s = wsum[0] + wsum[1] + wsum[2] + wsum[3];
        atomicAdd(&out[dir], s * (1.0f / (float)TOTALP));
    }
}

// ---------------------------------------------------------------------------
// Fallback for tiny workspace: direct 7-op kernel, no ws needed.
// ---------------------------------------------------------------------------
__global__ void zero_out_kernel(float* __restrict__ out)
{
    if (threadIdx.x == 0) { out[0] = 0.0f; out[1] = 0.0f; }
}

__global__ __launch_bounds__(256) void chamfer_raw_kernel(
    const float* __restrict__ xyz1, const float* __restrict__ xyz2,
    float* __restrict__ out)
{
    const int blk = blockIdx.x;
    const int dir = blk >> 8;
    const int idx = blk & 255;
    const int b   = idx >> 4;
    const int n0  = (idx & 15) << 8;

    const float* __restrict__ own = (dir == 0 ? xyz1 : xyz2) + (size_t)b * NPTS * 3;
    const float* __restrict__ opp = (dir == 0 ? xyz2 : xyz1) + (size_t)b * NPTS * 3;

    const int n = n0 + threadIdx.x;
    const float ax = own[3 * n + 0];
    const float ay = own[3 * n + 1];
    const float az = own[3 * n + 2];

    float best = FLT_MAX;
    for (int m = 0; m < NPTS; m += 4) {
#pragma unroll
        for (int u = 0; u < 4; ++u) {
            const float px = opp[3 * (m + u) + 0];
            const float py = opp[3 * (m + u) + 1];
            const float pz = opp[3 * (m + u) + 2];
            const float dx = px - ax, dy = py - ay, dz = pz - az;
            float d = dx * dx;
            d = fmaf(dy, dy, d);
            d = fmaf(dz, dz, d);
            best = fminf(best, d);
        }
    }

    float d = best;
    for (int off = 32; off > 0; off >>= 1)
        d += __shfl_down(d, off);

    __shared__ float wsum[4];
    const int lane = threadIdx.x & 63;
    const int wv   = threadIdx.x >> 6;
    if (lane == 0) wsum[wv] = d;
    __syncthreads();
    if (threadIdx.x == 0) {
        float s = wsum[0] + wsum[1] + wsum[2] + wsum[3];
        atomicAdd(&out[dir], s * (1.0f / (float)TOTALP));
    }
}

// ---------------------------------------------------------------------------
extern "C" void kernel_launch(void* const* d_in, const int* in_sizes, int n_in,
                              void* d_out, int out_size, void* d_ws, size_t ws_size,
                              hipStream_t stream)
{
    const float* xyz1 = (const float*)d_in[0];
    const float* xyz2 = (const float*)d_in[1];
    float* out = (float*)d_out;

    const size_t keys_bytes  = (size_t)NQ * sizeof(unsigned);   // 512 KiB
    const size_t packQ_bytes = (size_t)NQ * sizeof(uint4);      // 2 MiB
    const size_t plane_bytes = (size_t)2 * NQ * sizeof(uint4);  // 4 MiB

    if (ws_size >= keys_bytes + packQ_bytes + plane_bytes) {    // 6.5 MiB
        unsigned* keys   = (unsigned*)d_ws;
        uint4*    packQ  = (uint4*)((char*)d_ws + keys_bytes);
        uint4*    planes = (uint4*)((char*)d_ws + keys_bytes + packQ_bytes);

        prep_kernel<<<NQ / 256, 256, 0, stream>>>(xyz1, xyz2, packQ, planes, keys, out);
        // 2048 blocks: dir(2) x b(16) x qc(8) x ch(8) -> 8 blocks/CU
        chamfer_flip2<<<2048, 256, 0, stream>>>(packQ, planes, keys);
        chamfer_final_atomic<<<NQ / 256, 256, 0, stream>>>(keys, out);
    } else {
        zero_out_kernel<<<1, 64, 0, stream>>>(out);
        chamfer_raw_kernel<<<512, 256, 0, stream>>>(xyz1, xyz2, out);
    }
}